// Round 9
// baseline (431.646 us; speedup 1.0000x reference)
//
#include <hip/hip_runtime.h>

#define N_NODES 100000
#define N_EDGES 1600000
#define IN_DIM 256
#define HID 64
#define N_GRAPHS 100
#define NPART 256
#define PSTRIDE 128
#define BSHIFT 8
#define NBUCK 391   // ceil(N_NODES / 256)
#define CHUNK 4096  // edges per block in bucket passes

typedef __attribute__((ext_vector_type(8))) short short8;
typedef __attribute__((ext_vector_type(8))) unsigned short us8;
typedef __attribute__((ext_vector_type(4))) float floatx4;

// bf16 helpers (RNE)
__device__ __forceinline__ unsigned short f2b(float f) {
    unsigned int u = __float_as_uint(f);
    unsigned int r = (u + 0x7FFFu + ((u >> 16) & 1u)) >> 16;
    return (unsigned short)r;
}
__device__ __forceinline__ float b2f(unsigned short b) {
    return __uint_as_float(((unsigned int)b) << 16);
}

// ---------------- W prep: transpose + bf16 once ----------------

__global__ void k_wprep(const float* __restrict__ W1, const float* __restrict__ W2,
                        const float* __restrict__ W3,
                        unsigned short* __restrict__ wt1, unsigned short* __restrict__ wt2,
                        unsigned short* __restrict__ wt3) {
    int i = blockIdx.x * 256 + threadIdx.x;
    if (i < IN_DIM * HID) {
        int k = i >> 6, n = i & 63;
        wt1[n * IN_DIM + k] = f2b(W1[i]);
    }
    if (i < HID * HID) {
        int k = i >> 6, n = i & 63;
        wt2[n * HID + k] = f2b(W2[i]);
        wt3[n * HID + k] = f2b(W3[i]);
    }
}

// ---------------- bucketed edge partition ----------------

__global__ void k_zero_misc(int* __restrict__ bcount, float* __restrict__ partial) {
    int i = blockIdx.x * 256 + threadIdx.x;
    if (i < NBUCK) bcount[i] = 0;
    if (i < NPART * PSTRIDE) partial[i] = 0.f;
}

__global__ __launch_bounds__(256) void k_bhist(const int* __restrict__ dst,
                                               int* __restrict__ bcount) {
    __shared__ int lc[NBUCK];
    int t = threadIdx.x;
    for (int b = t; b < NBUCK; b += 256) lc[b] = 0;
    __syncthreads();
    int base = blockIdx.x * CHUNK;
#pragma unroll
    for (int i = 0; i < 16; ++i) {
        int e = base + i * 256 + t;
        if (e < N_EDGES) atomicAdd(&lc[dst[e] >> BSHIFT], 1);
    }
    __syncthreads();
    for (int b = t; b < NBUCK; b += 256)
        if (lc[b]) atomicAdd(&bcount[b], lc[b]);
}

__global__ void k_bscan(const int* __restrict__ bcount, int* __restrict__ bstart,
                        int* __restrict__ bfill) {
    __shared__ int s[512];
    int t = threadIdx.x;
    int v = (t < NBUCK) ? bcount[t] : 0;
    s[t] = v; __syncthreads();
    for (int off = 1; off < 512; off <<= 1) {
        int u = 0;
        if (t >= off) u = s[t - off];
        __syncthreads();
        s[t] += u;
        __syncthreads();
    }
    if (t < NBUCK) { int st = s[t] - v; bstart[t] = st; bfill[t] = st; }
    if (t == 0) bstart[NBUCK] = N_EDGES;
}

__global__ __launch_bounds__(256) void k_bscatter(const int* __restrict__ src,
                                                  const int* __restrict__ dst,
                                                  int* __restrict__ bfill,
                                                  int* __restrict__ ebuck) {
    __shared__ int lc[NBUCK];
    __shared__ int lb[NBUCK];
    int t = threadIdx.x;
    for (int b = t; b < NBUCK; b += 256) lc[b] = 0;
    __syncthreads();
    int base = blockIdx.x * CHUNK;
    int pk[16], bk[16], rk[16];
#pragma unroll
    for (int i = 0; i < 16; ++i) {
        int e = base + i * 256 + t;
        rk[i] = -1;
        if (e < N_EDGES) {
            int s = src[e], d = dst[e];
            bk[i] = d >> BSHIFT;
            pk[i] = (s << BSHIFT) | (d & 255);
            rk[i] = atomicAdd(&lc[bk[i]], 1);
        }
    }
    __syncthreads();
    for (int b = t; b < NBUCK; b += 256)
        lb[b] = lc[b] ? atomicAdd(&bfill[b], lc[b]) : 0;
    __syncthreads();
#pragma unroll
    for (int i = 0; i < 16; ++i)
        if (rk[i] >= 0) ebuck[lb[bk[i]] + rk[i]] = pk[i];
}

__global__ __launch_bounds__(256) void k_deg(const int* __restrict__ bstart,
                                             const int* __restrict__ ebuck,
                                             int* __restrict__ deg) {
    __shared__ int ld[256];
    int b = blockIdx.x, t = threadIdx.x;
    ld[t] = 1;  // self loop
    __syncthreads();
    int s = bstart[b], e = bstart[b + 1];
    for (int j = s + t; j < e; j += 256) atomicAdd(&ld[ebuck[j] & 255], 1);
    __syncthreads();
    int node = (b << BSHIFT) + t;
    if (node < N_NODES) deg[node] = ld[t];
}

// ---------------- rowptr scan ----------------

__global__ void k_scan1(const int* __restrict__ deg, float* __restrict__ dinv,
                        int* __restrict__ bsum) {
    __shared__ int s[256];
    int t = threadIdx.x;
    int i = blockIdx.x * 256 + t;
    int c = 0;
    if (i < N_NODES) {
        int d = deg[i];
        dinv[i] = rsqrtf((float)d);
        c = d - 1;
    }
    s[t] = c; __syncthreads();
    for (int off = 128; off; off >>= 1) {
        if (t < off) s[t] += s[t + off];
        __syncthreads();
    }
    if (t == 0) bsum[blockIdx.x] = s[0];
}

__global__ void k_scan2(const int* __restrict__ bsum, int* __restrict__ bscan, int nb) {
    __shared__ int s[512];
    int t = threadIdx.x;
    int v = (t < nb) ? bsum[t] : 0;
    s[t] = v; __syncthreads();
    for (int off = 1; off < 512; off <<= 1) {
        int u = 0;
        if (t >= off) u = s[t - off];
        __syncthreads();
        s[t] += u;
        __syncthreads();
    }
    if (t < nb) bscan[t] = s[t] - v;
}

__global__ void k_scan3(const int* __restrict__ deg, const int* __restrict__ bscan,
                        int* __restrict__ rowptr) {
    __shared__ int s[256];
    int t = threadIdx.x;
    int i = blockIdx.x * 256 + t;
    int c = (i < N_NODES) ? deg[i] - 1 : 0;
    s[t] = c; __syncthreads();
    for (int off = 1; off < 256; off <<= 1) {
        int u = 0;
        if (t >= off) u = s[t - off];
        __syncthreads();
        s[t] += u;
        __syncthreads();
    }
    if (i < N_NODES) rowptr[i] = bscan[blockIdx.x] + s[t] - c;  // exclusive
}

// CSR fill: col only (weights folded into dinv-prescaled T)
__global__ __launch_bounds__(256) void k_fill(const int* __restrict__ bstart,
                                              const int* __restrict__ ebuck,
                                              const int* __restrict__ rowptr,
                                              int* __restrict__ col) {
    __shared__ int lf[256];
    int b = blockIdx.x, t = threadIdx.x;
    int node = (b << BSHIFT) + t;
    lf[t] = (node < N_NODES) ? rowptr[node] : 0;
    __syncthreads();
    int s = bstart[b], e = bstart[b + 1];
    for (int j = s + t; j < e; j += 256) {
        int v = ebuck[j];
        int pos = atomicAdd(&lf[v & 255], 1);
        col[pos] = v >> BSHIFT;
    }
}

// ---------------- MFMA GEMM1: Tb = dinv * (X[fp32] @ W1) ----------------
// A-fragments are wave-private -> load DIRECTLY from global (no X LDS, no
// k-loop barriers; compiler pipelines the loads). Only W lives in LDS,
// staged once. 64 rows/block (4 waves x 16 rows), 1563 blocks.

__global__ __launch_bounds__(256) void k_gemm1(const float* __restrict__ X,
                                               const unsigned short* __restrict__ Wt,
                                               const float* __restrict__ dinv,
                                               unsigned short* __restrict__ Tb) {
    __shared__ unsigned short Wb[64][264];   // 33.8 KB, row pad 264 (odd granules)
    const int t = threadIdx.x;
    const int lane = t & 63, wv = t >> 6;
    const int fl = lane & 15, quad = lane >> 4;
    const int r0 = blockIdx.x * 64;

    // stage W once: 64 x 256 bf16 = 2048 us8 granules / 256 thr = 8 each
    for (int g = t; g < 64 * 32; g += 256) {
        int n = g >> 5, kc8 = g & 31;
        *(us8*)&Wb[n][kc8 * 8] = *(const us8*)(Wt + n * IN_DIM + kc8 * 8);
    }

    const int arow = r0 + wv * 16 + fl;
    const bool valid = arow < N_NODES;
    const float* xp = X + (size_t)(valid ? arow : 0) * IN_DIM;

    floatx4 acc[4];
#pragma unroll
    for (int j = 0; j < 4; ++j) acc[j] = (floatx4){0.f, 0.f, 0.f, 0.f};

    __syncthreads();

#pragma unroll
    for (int kc = 0; kc < IN_DIM; kc += 32) {
        float4 x0 = make_float4(0.f, 0.f, 0.f, 0.f);
        float4 x1 = make_float4(0.f, 0.f, 0.f, 0.f);
        if (valid) {
            x0 = *(const float4*)(xp + kc + quad * 8);
            x1 = *(const float4*)(xp + kc + quad * 8 + 4);
        }
        short8 a;
        a[0] = (short)f2b(x0.x); a[1] = (short)f2b(x0.y);
        a[2] = (short)f2b(x0.z); a[3] = (short)f2b(x0.w);
        a[4] = (short)f2b(x1.x); a[5] = (short)f2b(x1.y);
        a[6] = (short)f2b(x1.z); a[7] = (short)f2b(x1.w);
#pragma unroll
        for (int ct = 0; ct < 4; ++ct) {
            short8 b = *(const short8*)&Wb[ct * 16 + fl][kc + quad * 8];
            acc[ct] = __builtin_amdgcn_mfma_f32_16x16x32_bf16(a, b, acc[ct], 0, 0, 0);
        }
    }

    int rbase = r0 + wv * 16 + quad * 4;
#pragma unroll
    for (int r = 0; r < 4; ++r) {
        int row = rbase + r;
        if (row < N_NODES) {
            float di = dinv[row];
#pragma unroll
            for (int ct = 0; ct < 4; ++ct)
                Tb[(size_t)row * HID + ct * 16 + fl] = f2b(di * acc[ct][r]);
        }
    }
}

// ---------------- MFMA GEMM2/3: Tb = dinv * (Hb[bf16] @ W) ----------------
// Same barrier-free structure; W = 8 KB LDS.

__global__ __launch_bounds__(256) void k_gemm2(const unsigned short* __restrict__ Xin,
                                               const unsigned short* __restrict__ Wt,
                                               const float* __restrict__ dinv,
                                               unsigned short* __restrict__ Tb) {
    __shared__ unsigned short Wb[64][72];
    const int t = threadIdx.x;
    const int lane = t & 63, wv = t >> 6;
    const int fl = lane & 15, quad = lane >> 4;
    const int r0 = blockIdx.x * 64;

    for (int g = t; g < 64 * 8; g += 256) {
        int n = g >> 3, kc8 = g & 7;
        *(us8*)&Wb[n][kc8 * 8] = *(const us8*)(Wt + n * HID + kc8 * 8);
    }

    const int arow = r0 + wv * 16 + fl;
    const bool valid = arow < N_NODES;
    const unsigned short* xp = Xin + (size_t)(valid ? arow : 0) * HID;

    floatx4 acc[4];
#pragma unroll
    for (int j = 0; j < 4; ++j) acc[j] = (floatx4){0.f, 0.f, 0.f, 0.f};

    __syncthreads();

#pragma unroll
    for (int kc = 0; kc < HID; kc += 32) {
        short8 a = (short8){0, 0, 0, 0, 0, 0, 0, 0};
        if (valid) a = *(const short8*)(xp + kc + quad * 8);
#pragma unroll
        for (int ct = 0; ct < 4; ++ct) {
            short8 b = *(const short8*)&Wb[ct * 16 + fl][kc + quad * 8];
            acc[ct] = __builtin_amdgcn_mfma_f32_16x16x32_bf16(a, b, acc[ct], 0, 0, 0);
        }
    }

    int rbase = r0 + wv * 16 + quad * 4;
#pragma unroll
    for (int r = 0; r < 4; ++r) {
        int row = rbase + r;
        if (row < N_NODES) {
            float di = dinv[row];
#pragma unroll
            for (int ct = 0; ct < 4; ++ct)
                Tb[(size_t)row * HID + ct * 16 + fl] = f2b(di * acc[ct][r]);
        }
    }
}

// ---------------- aggregation: H[i] = relu(dinv[i]*(Tb[i] + sum_e Tb[src]) + b) ----------------
// Wave per node. grp=lane>>3 covers 8 edges/instr, fl=lane&7 covers 8 features
// (ushort8 = 16 B/lane). Gather instr = 64 lanes x 16 B = 1 KB spanning 8 edges.

__global__ __launch_bounds__(256) void k_agg(const unsigned short* __restrict__ Tb,
                                             const int* __restrict__ rowptr,
                                             const int* __restrict__ deg,
                                             const float* __restrict__ dinv,
                                             const int* __restrict__ col,
                                             const float* __restrict__ bias,
                                             unsigned short* __restrict__ Hb) {
    int lane = threadIdx.x & 63;
    int node = blockIdx.x * 4 + (threadIdx.x >> 6);
    int grp = lane >> 3, fl = lane & 7;
    int e = __builtin_amdgcn_readfirstlane(rowptr[node]);
    int end = e + __builtin_amdgcn_readfirstlane(deg[node]) - 1;
    float a0 = 0.f, a1 = 0.f, a2 = 0.f, a3 = 0.f;
    float a4 = 0.f, a5 = 0.f, a6 = 0.f, a7 = 0.f;
    for (; e + 8 <= end; e += 8) {
        int s = col[e + grp];
        us8 tv = *(const us8*)(Tb + (size_t)s * HID + fl * 8);
        a0 += b2f(tv[0]); a1 += b2f(tv[1]); a2 += b2f(tv[2]); a3 += b2f(tv[3]);
        a4 += b2f(tv[4]); a5 += b2f(tv[5]); a6 += b2f(tv[6]); a7 += b2f(tv[7]);
    }
    if (e + grp < end) {
        int s = col[e + grp];
        us8 tv = *(const us8*)(Tb + (size_t)s * HID + fl * 8);
        a0 += b2f(tv[0]); a1 += b2f(tv[1]); a2 += b2f(tv[2]); a3 += b2f(tv[3]);
        a4 += b2f(tv[4]); a5 += b2f(tv[5]); a6 += b2f(tv[6]); a7 += b2f(tv[7]);
    }
    a0 += __shfl_xor(a0, 8);  a1 += __shfl_xor(a1, 8);
    a2 += __shfl_xor(a2, 8);  a3 += __shfl_xor(a3, 8);
    a4 += __shfl_xor(a4, 8);  a5 += __shfl_xor(a5, 8);
    a6 += __shfl_xor(a6, 8);  a7 += __shfl_xor(a7, 8);
    a0 += __shfl_xor(a0, 16); a1 += __shfl_xor(a1, 16);
    a2 += __shfl_xor(a2, 16); a3 += __shfl_xor(a3, 16);
    a4 += __shfl_xor(a4, 16); a5 += __shfl_xor(a5, 16);
    a6 += __shfl_xor(a6, 16); a7 += __shfl_xor(a7, 16);
    a0 += __shfl_xor(a0, 32); a1 += __shfl_xor(a1, 32);
    a2 += __shfl_xor(a2, 32); a3 += __shfl_xor(a3, 32);
    a4 += __shfl_xor(a4, 32); a5 += __shfl_xor(a5, 32);
    a6 += __shfl_xor(a6, 32); a7 += __shfl_xor(a7, 32);
    us8 sv = *(const us8*)(Tb + (size_t)node * HID + fl * 8);
    a0 += b2f(sv[0]); a1 += b2f(sv[1]); a2 += b2f(sv[2]); a3 += b2f(sv[3]);
    a4 += b2f(sv[4]); a5 += b2f(sv[5]); a6 += b2f(sv[6]); a7 += b2f(sv[7]);
    float di = dinv[node];
    float4 b0 = *(const float4*)(bias + fl * 8);
    float4 b1v = *(const float4*)(bias + fl * 8 + 4);
    a0 = fmaxf(fmaf(di, a0, b0.x), 0.f);
    a1 = fmaxf(fmaf(di, a1, b0.y), 0.f);
    a2 = fmaxf(fmaf(di, a2, b0.z), 0.f);
    a3 = fmaxf(fmaf(di, a3, b0.w), 0.f);
    a4 = fmaxf(fmaf(di, a4, b1v.x), 0.f);
    a5 = fmaxf(fmaf(di, a5, b1v.y), 0.f);
    a6 = fmaxf(fmaf(di, a6, b1v.z), 0.f);
    a7 = fmaxf(fmaf(di, a7, b1v.w), 0.f);
    if (grp == 0) {
        us8 o;
        o[0] = f2b(a0); o[1] = f2b(a1); o[2] = f2b(a2); o[3] = f2b(a3);
        o[4] = f2b(a4); o[5] = f2b(a5); o[6] = f2b(a6); o[7] = f2b(a7);
        *(us8*)(Hb + (size_t)node * HID + fl * 8) = o;
    }
}

// layer-3 aggregation (no relu) fused with pooling + final linear
__global__ __launch_bounds__(256) void k_agg_pool(const unsigned short* __restrict__ Tb,
                                                  const int* __restrict__ rowptr,
                                                  const int* __restrict__ deg,
                                                  const float* __restrict__ dinv,
                                                  const int* __restrict__ col,
                                                  const float* __restrict__ bias,
                                                  const float* __restrict__ Wl,
                                                  const int* __restrict__ batch,
                                                  float* __restrict__ partial) {
    int lane = threadIdx.x & 63;
    int node = blockIdx.x * 4 + (threadIdx.x >> 6);
    int grp = lane >> 3, fl = lane & 7;
    int e = __builtin_amdgcn_readfirstlane(rowptr[node]);
    int end = e + __builtin_amdgcn_readfirstlane(deg[node]) - 1;
    float a0 = 0.f, a1 = 0.f, a2 = 0.f, a3 = 0.f;
    float a4 = 0.f, a5 = 0.f, a6 = 0.f, a7 = 0.f;
    for (; e + 8 <= end; e += 8) {
        int s = col[e + grp];
        us8 tv = *(const us8*)(Tb + (size_t)s * HID + fl * 8);
        a0 += b2f(tv[0]); a1 += b2f(tv[1]); a2 += b2f(tv[2]); a3 += b2f(tv[3]);
        a4 += b2f(tv[4]); a5 += b2f(tv[5]); a6 += b2f(tv[6]); a7 += b2f(tv[7]);
    }
    if (e + grp < end) {
        int s = col[e + grp];
        us8 tv = *(const us8*)(Tb + (size_t)s * HID + fl * 8);
        a0 += b2f(tv[0]); a1 += b2f(tv[1]); a2 += b2f(tv[2]); a3 += b2f(tv[3]);
        a4 += b2f(tv[4]); a5 += b2f(tv[5]); a6 += b2f(tv[6]); a7 += b2f(tv[7]);
    }
    a0 += __shfl_xor(a0, 8);  a1 += __shfl_xor(a1, 8);
    a2 += __shfl_xor(a2, 8);  a3 += __shfl_xor(a3, 8);
    a4 += __shfl_xor(a4, 8);  a5 += __shfl_xor(a5, 8);
    a6 += __shfl_xor(a6, 8);  a7 += __shfl_xor(a7, 8);
    a0 += __shfl_xor(a0, 16); a1 += __shfl_xor(a1, 16);
    a2 += __shfl_xor(a2, 16); a3 += __shfl_xor(a3, 16);
    a4 += __shfl_xor(a4, 16); a5 += __shfl_xor(a5, 16);
    a6 += __shfl_xor(a6, 16); a7 += __shfl_xor(a7, 16);
    a0 += __shfl_xor(a0, 32); a1 += __shfl_xor(a1, 32);
    a2 += __shfl_xor(a2, 32); a3 += __shfl_xor(a3, 32);
    a4 += __shfl_xor(a4, 32); a5 += __shfl_xor(a5, 32);
    a6 += __shfl_xor(a6, 32); a7 += __shfl_xor(a7, 32);
    us8 sv = *(const us8*)(Tb + (size_t)node * HID + fl * 8);
    a0 += b2f(sv[0]); a1 += b2f(sv[1]); a2 += b2f(sv[2]); a3 += b2f(sv[3]);
    a4 += b2f(sv[4]); a5 += b2f(sv[5]); a6 += b2f(sv[6]); a7 += b2f(sv[7]);
    float di = dinv[node];
    float4 b0 = *(const float4*)(bias + fl * 8);
    float4 b1v = *(const float4*)(bias + fl * 8 + 4);
    a0 = fmaf(di, a0, b0.x);
    a1 = fmaf(di, a1, b0.y);
    a2 = fmaf(di, a2, b0.z);
    a3 = fmaf(di, a3, b0.w);
    a4 = fmaf(di, a4, b1v.x);
    a5 = fmaf(di, a5, b1v.y);
    a6 = fmaf(di, a6, b1v.z);
    a7 = fmaf(di, a7, b1v.w);
    float4 w0 = *(const float4*)(Wl + fl * 8);
    float4 w1 = *(const float4*)(Wl + fl * 8 + 4);
    float s = a0 * w0.x + a1 * w0.y + a2 * w0.z + a3 * w0.w +
              a4 * w1.x + a5 * w1.y + a6 * w1.z + a7 * w1.w;
    s += __shfl_xor(s, 1);
    s += __shfl_xor(s, 2);
    s += __shfl_xor(s, 4);
    if (lane == 0)
        atomicAdd(&partial[(blockIdx.x & (NPART - 1)) * PSTRIDE + batch[node]], s);
}

__global__ void k_pool_reduce(const float* __restrict__ partial,
                              const float* __restrict__ bl,
                              float* __restrict__ out) {
    int g = threadIdx.x;
    if (g >= N_GRAPHS) return;
    float s = bl[0];
    for (int p = 0; p < NPART; ++p) s += partial[p * PSTRIDE + g];
    out[g] = s;
}

extern "C" void kernel_launch(void* const* d_in, const int* in_sizes, int n_in,
                              void* d_out, int out_size, void* d_ws, size_t ws_size,
                              hipStream_t stream) {
    const float* x     = (const float*)d_in[0];
    const int*   ei    = (const int*)d_in[1];
    const int*   batch = (const int*)d_in[2];
    const float* W1    = (const float*)d_in[3];
    const float* b1    = (const float*)d_in[4];
    const float* W2    = (const float*)d_in[5];
    const float* b2    = (const float*)d_in[6];
    const float* W3    = (const float*)d_in[7];
    const float* b3    = (const float*)d_in[8];
    const float* Wl    = (const float*)d_in[9];
    const float* bl    = (const float*)d_in[10];
    float* out = (float*)d_out;

    char* p = (char*)d_ws;
    unsigned short* tb = (unsigned short*)p; p += (size_t)N_NODES * HID * 2;  // 12.8 MB
    unsigned short* hB = (unsigned short*)p; p += (size_t)N_NODES * HID * 2;  // 12.8 MB
    int*   col     = (int*)p;   p += (size_t)(N_EDGES + 16) * 4;              // 6.4 MB
    int*   ebuck   = (int*)p;   p += (size_t)N_EDGES * 4;                     // 6.4 MB
    int*   deg     = (int*)p;   p += (size_t)N_NODES * 4;
    float* dinv    = (float*)p; p += (size_t)N_NODES * 4;
    int*   rowptr  = (int*)p;   p += (size_t)N_NODES * 4;
    int*   bcount  = (int*)p;   p += (NBUCK + 1) * 4;
    int*   bstart  = (int*)p;   p += (NBUCK + 1) * 4;
    int*   bfill   = (int*)p;   p += (NBUCK + 1) * 4;
    int*   bsum    = (int*)p;   p += 512 * 4;
    int*   bscan   = (int*)p;   p += 512 * 4;
    float* partial = (float*)p; p += (size_t)NPART * PSTRIDE * 4;
    unsigned short* wt1 = (unsigned short*)p; p += (size_t)IN_DIM * HID * 2;
    unsigned short* wt2 = (unsigned short*)p; p += (size_t)HID * HID * 2;
    unsigned short* wt3 = (unsigned short*)p; p += (size_t)HID * HID * 2;

    const int* src  = ei;
    const int* dstp = ei + N_EDGES;

    const int nb = (N_NODES + 255) / 256;            // 391
    const int cb = (N_EDGES + CHUNK - 1) / CHUNK;    // 391
    const int gemm_blocks = (N_NODES + 63) / 64;     // 1563
    const int node_wave_blocks = (N_NODES + 3) / 4;  // 25000

    k_wprep<<<(IN_DIM * HID + 255) / 256, 256, 0, stream>>>(W1, W2, W3, wt1, wt2, wt3);
    k_zero_misc<<<(NPART * PSTRIDE + 255) / 256, 256, 0, stream>>>(bcount, partial);
    k_bhist<<<cb, 256, 0, stream>>>(dstp, bcount);
    k_bscan<<<1, 512, 0, stream>>>(bcount, bstart, bfill);
    k_bscatter<<<cb, 256, 0, stream>>>(src, dstp, bfill, ebuck);
    k_deg<<<NBUCK, 256, 0, stream>>>(bstart, ebuck, deg);
    k_scan1<<<nb, 256, 0, stream>>>(deg, dinv, bsum);
    k_scan2<<<1, 512, 0, stream>>>(bsum, bscan, nb);
    k_scan3<<<nb, 256, 0, stream>>>(deg, bscan, rowptr);
    k_fill<<<NBUCK, 256, 0, stream>>>(bstart, ebuck, rowptr, col);

    k_gemm1<<<gemm_blocks, 256, 0, stream>>>(x, wt1, dinv, tb);
    k_agg<<<node_wave_blocks, 256, 0, stream>>>(tb, rowptr, deg, dinv, col, b1, hB);
    k_gemm2<<<gemm_blocks, 256, 0, stream>>>(hB, wt2, dinv, tb);
    k_agg<<<node_wave_blocks, 256, 0, stream>>>(tb, rowptr, deg, dinv, col, b2, hB);
    k_gemm2<<<gemm_blocks, 256, 0, stream>>>(hB, wt3, dinv, tb);
    k_agg_pool<<<node_wave_blocks, 256, 0, stream>>>(tb, rowptr, deg, dinv, col, b3,
                                                     Wl, batch, partial);

    k_pool_reduce<<<1, 128, 0, stream>>>(partial, bl, out);
}

// Round 10
// 386.477 us; speedup vs baseline: 1.1169x; 1.1169x over previous
//
#include <hip/hip_runtime.h>

#define N_NODES 100000
#define N_EDGES 1600000
#define IN_DIM 256
#define HID 64
#define N_GRAPHS 100
#define NPART 256
#define PSTRIDE 128
#define BSHIFT 8
#define NBUCK 391   // ceil(N_NODES / 256)
#define CHUNK 4096  // edges per block in bucket passes

typedef __attribute__((ext_vector_type(8))) short short8;
typedef __attribute__((ext_vector_type(8))) unsigned short us8;
typedef __attribute__((ext_vector_type(4))) float floatx4;

// bf16 helpers (RNE)
__device__ __forceinline__ unsigned short f2b(float f) {
    unsigned int u = __float_as_uint(f);
    unsigned int r = (u + 0x7FFFu + ((u >> 16) & 1u)) >> 16;
    return (unsigned short)r;
}
__device__ __forceinline__ float b2f(unsigned short b) {
    return __uint_as_float(((unsigned int)b) << 16);
}

// ---------------- W prep: transpose + bf16 once; w3l = W3@Wl, b3wl = b3.Wl ----------------

__global__ void k_wprep(const float* __restrict__ W1, const float* __restrict__ W2,
                        const float* __restrict__ W3, const float* __restrict__ Wl,
                        const float* __restrict__ b3,
                        unsigned short* __restrict__ wt1, unsigned short* __restrict__ wt2,
                        float* __restrict__ w3l) {
    int i = blockIdx.x * 256 + threadIdx.x;
    if (i < IN_DIM * HID) {
        int k = i >> 6, n = i & 63;
        wt1[n * IN_DIM + k] = f2b(W1[i]);
    }
    if (i < HID * HID) {
        int k = i >> 6, n = i & 63;
        wt2[n * HID + k] = f2b(W2[i]);
    }
    if (blockIdx.x == 0) {
        int t = threadIdx.x;
        if (t < HID) {
            float s = 0.f;
            for (int n = 0; n < HID; ++n) s += W3[t * HID + n] * Wl[n];
            w3l[t] = s;
        } else if (t == HID) {
            float s = 0.f;
            for (int n = 0; n < HID; ++n) s += b3[n] * Wl[n];
            w3l[HID] = s;  // b3wl
        }
    }
}

// ---------------- bucketed edge partition ----------------

__global__ void k_zero_misc(int* __restrict__ bcount, float* __restrict__ partial) {
    int i = blockIdx.x * 256 + threadIdx.x;
    if (i < NBUCK) bcount[i] = 0;
    if (i < NPART * PSTRIDE) partial[i] = 0.f;
}

__global__ __launch_bounds__(256) void k_bhist(const int* __restrict__ dst,
                                               int* __restrict__ bcount) {
    __shared__ int lc[NBUCK];
    int t = threadIdx.x;
    for (int b = t; b < NBUCK; b += 256) lc[b] = 0;
    __syncthreads();
    int base = blockIdx.x * CHUNK;
#pragma unroll
    for (int i = 0; i < 16; ++i) {
        int e = base + i * 256 + t;
        if (e < N_EDGES) atomicAdd(&lc[dst[e] >> BSHIFT], 1);
    }
    __syncthreads();
    for (int b = t; b < NBUCK; b += 256)
        if (lc[b]) atomicAdd(&bcount[b], lc[b]);
}

__global__ void k_bscan(const int* __restrict__ bcount, int* __restrict__ bstart,
                        int* __restrict__ bfill) {
    __shared__ int s[512];
    int t = threadIdx.x;
    int v = (t < NBUCK) ? bcount[t] : 0;
    s[t] = v; __syncthreads();
    for (int off = 1; off < 512; off <<= 1) {
        int u = 0;
        if (t >= off) u = s[t - off];
        __syncthreads();
        s[t] += u;
        __syncthreads();
    }
    if (t < NBUCK) { int st = s[t] - v; bstart[t] = st; bfill[t] = st; }
    if (t == 0) bstart[NBUCK] = N_EDGES;
}

__global__ __launch_bounds__(256) void k_bscatter(const int* __restrict__ src,
                                                  const int* __restrict__ dst,
                                                  int* __restrict__ bfill,
                                                  int* __restrict__ ebuck) {
    __shared__ int lc[NBUCK];
    __shared__ int lb[NBUCK];
    int t = threadIdx.x;
    for (int b = t; b < NBUCK; b += 256) lc[b] = 0;
    __syncthreads();
    int base = blockIdx.x * CHUNK;
    int pk[16], bk[16], rk[16];
#pragma unroll
    for (int i = 0; i < 16; ++i) {
        int e = base + i * 256 + t;
        rk[i] = -1;
        if (e < N_EDGES) {
            int s = src[e], d = dst[e];
            bk[i] = d >> BSHIFT;
            pk[i] = (s << BSHIFT) | (d & 255);
            rk[i] = atomicAdd(&lc[bk[i]], 1);
        }
    }
    __syncthreads();
    for (int b = t; b < NBUCK; b += 256)
        lb[b] = lc[b] ? atomicAdd(&bfill[b], lc[b]) : 0;
    __syncthreads();
#pragma unroll
    for (int i = 0; i < 16; ++i)
        if (rk[i] >= 0) ebuck[lb[bk[i]] + rk[i]] = pk[i];
}

// fused: per-bucket degree histogram + dinv + block-sum of (deg-1) for rowptr scan
__global__ __launch_bounds__(256) void k_degscan(const int* __restrict__ bstart,
                                                 const int* __restrict__ ebuck,
                                                 int* __restrict__ deg,
                                                 float* __restrict__ dinv,
                                                 int* __restrict__ bsum) {
    __shared__ int ld[256];
    __shared__ int rs[256];
    int b = blockIdx.x, t = threadIdx.x;
    ld[t] = 1;  // self loop
    __syncthreads();
    int s = bstart[b], e = bstart[b + 1];
    for (int j = s + t; j < e; j += 256) atomicAdd(&ld[ebuck[j] & 255], 1);
    __syncthreads();
    int node = (b << BSHIFT) + t;
    int d = ld[t];
    if (node < N_NODES) {
        deg[node] = d;
        dinv[node] = rsqrtf((float)d);
    }
    rs[t] = (node < N_NODES) ? d - 1 : 0;
    __syncthreads();
    for (int off = 128; off; off >>= 1) {
        if (t < off) rs[t] += rs[t + off];
        __syncthreads();
    }
    if (t == 0) bsum[b] = rs[0];
}

__global__ void k_scan2(const int* __restrict__ bsum, int* __restrict__ bscan, int nb) {
    __shared__ int s[512];
    int t = threadIdx.x;
    int v = (t < nb) ? bsum[t] : 0;
    s[t] = v; __syncthreads();
    for (int off = 1; off < 512; off <<= 1) {
        int u = 0;
        if (t >= off) u = s[t - off];
        __syncthreads();
        s[t] += u;
        __syncthreads();
    }
    if (t < nb) bscan[t] = s[t] - v;
}

// fused: in-bucket exclusive scan of deg -> rowptr, then CSR fill from ebuck
__global__ __launch_bounds__(256) void k_fill2(const int* __restrict__ bstart,
                                               const int* __restrict__ ebuck,
                                               const int* __restrict__ deg,
                                               const int* __restrict__ bscan,
                                               int* __restrict__ rowptr,
                                               int* __restrict__ col) {
    __shared__ int s[256];
    __shared__ int lf[256];
    int b = blockIdx.x, t = threadIdx.x;
    int node = (b << BSHIFT) + t;
    int c = (node < N_NODES) ? deg[node] - 1 : 0;
    s[t] = c; __syncthreads();
    for (int off = 1; off < 256; off <<= 1) {
        int u = 0;
        if (t >= off) u = s[t - off];
        __syncthreads();
        s[t] += u;
        __syncthreads();
    }
    int pos = bscan[b] + s[t] - c;  // exclusive
    if (node < N_NODES) rowptr[node] = pos;
    lf[t] = pos;
    __syncthreads();
    int st = bstart[b], e = bstart[b + 1];
    for (int j = st + t; j < e; j += 256) {
        int v = ebuck[j];
        int p = atomicAdd(&lf[v & 255], 1);
        col[p] = v >> BSHIFT;
    }
}

// ---------------- MFMA GEMM1: Tb = dinv * (X[fp32] @ W1) ----------------
// A-fragments wave-private -> direct global loads, no k-loop barriers.

__global__ __launch_bounds__(256) void k_gemm1(const float* __restrict__ X,
                                               const unsigned short* __restrict__ Wt,
                                               const float* __restrict__ dinv,
                                               unsigned short* __restrict__ Tb) {
    __shared__ unsigned short Wb[64][264];
    const int t = threadIdx.x;
    const int lane = t & 63, wv = t >> 6;
    const int fl = lane & 15, quad = lane >> 4;
    const int r0 = blockIdx.x * 64;

    for (int g = t; g < 64 * 32; g += 256) {
        int n = g >> 5, kc8 = g & 31;
        *(us8*)&Wb[n][kc8 * 8] = *(const us8*)(Wt + n * IN_DIM + kc8 * 8);
    }

    const int arow = r0 + wv * 16 + fl;
    const bool valid = arow < N_NODES;
    const float* xp = X + (size_t)(valid ? arow : 0) * IN_DIM;

    floatx4 acc[4];
#pragma unroll
    for (int j = 0; j < 4; ++j) acc[j] = (floatx4){0.f, 0.f, 0.f, 0.f};

    __syncthreads();

#pragma unroll
    for (int kc = 0; kc < IN_DIM; kc += 32) {
        float4 x0 = make_float4(0.f, 0.f, 0.f, 0.f);
        float4 x1 = make_float4(0.f, 0.f, 0.f, 0.f);
        if (valid) {
            x0 = *(const float4*)(xp + kc + quad * 8);
            x1 = *(const float4*)(xp + kc + quad * 8 + 4);
        }
        short8 a;
        a[0] = (short)f2b(x0.x); a[1] = (short)f2b(x0.y);
        a[2] = (short)f2b(x0.z); a[3] = (short)f2b(x0.w);
        a[4] = (short)f2b(x1.x); a[5] = (short)f2b(x1.y);
        a[6] = (short)f2b(x1.z); a[7] = (short)f2b(x1.w);
#pragma unroll
        for (int ct = 0; ct < 4; ++ct) {
            short8 b = *(const short8*)&Wb[ct * 16 + fl][kc + quad * 8];
            acc[ct] = __builtin_amdgcn_mfma_f32_16x16x32_bf16(a, b, acc[ct], 0, 0, 0);
        }
    }

    int rbase = r0 + wv * 16 + quad * 4;
#pragma unroll
    for (int r = 0; r < 4; ++r) {
        int row = rbase + r;
        if (row < N_NODES) {
            float di = dinv[row];
#pragma unroll
            for (int ct = 0; ct < 4; ++ct)
                Tb[(size_t)row * HID + ct * 16 + fl] = f2b(di * acc[ct][r]);
        }
    }
}

// ---------------- MFMA GEMM2: Tb = dinv * (Hb[bf16] @ W) ----------------

__global__ __launch_bounds__(256) void k_gemm2(const unsigned short* __restrict__ Xin,
                                               const unsigned short* __restrict__ Wt,
                                               const float* __restrict__ dinv,
                                               unsigned short* __restrict__ Tb) {
    __shared__ unsigned short Wb[64][72];
    const int t = threadIdx.x;
    const int lane = t & 63, wv = t >> 6;
    const int fl = lane & 15, quad = lane >> 4;
    const int r0 = blockIdx.x * 64;

    for (int g = t; g < 64 * 8; g += 256) {
        int n = g >> 3, kc8 = g & 7;
        *(us8*)&Wb[n][kc8 * 8] = *(const us8*)(Wt + n * HID + kc8 * 8);
    }

    const int arow = r0 + wv * 16 + fl;
    const bool valid = arow < N_NODES;
    const unsigned short* xp = Xin + (size_t)(valid ? arow : 0) * HID;

    floatx4 acc[4];
#pragma unroll
    for (int j = 0; j < 4; ++j) acc[j] = (floatx4){0.f, 0.f, 0.f, 0.f};

    __syncthreads();

#pragma unroll
    for (int kc = 0; kc < HID; kc += 32) {
        short8 a = (short8){0, 0, 0, 0, 0, 0, 0, 0};
        if (valid) a = *(const short8*)(xp + kc + quad * 8);
#pragma unroll
        for (int ct = 0; ct < 4; ++ct) {
            short8 b = *(const short8*)&Wb[ct * 16 + fl][kc + quad * 8];
            acc[ct] = __builtin_amdgcn_mfma_f32_16x16x32_bf16(a, b, acc[ct], 0, 0, 0);
        }
    }

    int rbase = r0 + wv * 16 + quad * 4;
#pragma unroll
    for (int r = 0; r < 4; ++r) {
        int row = rbase + r;
        if (row < N_NODES) {
            float di = dinv[row];
#pragma unroll
            for (int ct = 0; ct < 4; ++ct)
                Tb[(size_t)row * HID + ct * 16 + fl] = f2b(di * acc[ct][r]);
        }
    }
}

// ---------------- aggregation (layers 1-2): H[i] = relu(dinv[i]*(Tb[i]+sum Tb[src])+b) ----------------

__global__ __launch_bounds__(256) void k_agg(const unsigned short* __restrict__ Tb,
                                             const int* __restrict__ rowptr,
                                             const int* __restrict__ deg,
                                             const float* __restrict__ dinv,
                                             const int* __restrict__ col,
                                             const float* __restrict__ bias,
                                             unsigned short* __restrict__ Hb) {
    int lane = threadIdx.x & 63;
    int node = blockIdx.x * 4 + (threadIdx.x >> 6);
    int grp = lane >> 3, fl = lane & 7;
    int e = __builtin_amdgcn_readfirstlane(rowptr[node]);
    int end = e + __builtin_amdgcn_readfirstlane(deg[node]) - 1;
    float a0 = 0.f, a1 = 0.f, a2 = 0.f, a3 = 0.f;
    float a4 = 0.f, a5 = 0.f, a6 = 0.f, a7 = 0.f;
    for (; e + 8 <= end; e += 8) {
        int s = col[e + grp];
        us8 tv = *(const us8*)(Tb + (size_t)s * HID + fl * 8);
        a0 += b2f(tv[0]); a1 += b2f(tv[1]); a2 += b2f(tv[2]); a3 += b2f(tv[3]);
        a4 += b2f(tv[4]); a5 += b2f(tv[5]); a6 += b2f(tv[6]); a7 += b2f(tv[7]);
    }
    if (e + grp < end) {
        int s = col[e + grp];
        us8 tv = *(const us8*)(Tb + (size_t)s * HID + fl * 8);
        a0 += b2f(tv[0]); a1 += b2f(tv[1]); a2 += b2f(tv[2]); a3 += b2f(tv[3]);
        a4 += b2f(tv[4]); a5 += b2f(tv[5]); a6 += b2f(tv[6]); a7 += b2f(tv[7]);
    }
    a0 += __shfl_xor(a0, 8);  a1 += __shfl_xor(a1, 8);
    a2 += __shfl_xor(a2, 8);  a3 += __shfl_xor(a3, 8);
    a4 += __shfl_xor(a4, 8);  a5 += __shfl_xor(a5, 8);
    a6 += __shfl_xor(a6, 8);  a7 += __shfl_xor(a7, 8);
    a0 += __shfl_xor(a0, 16); a1 += __shfl_xor(a1, 16);
    a2 += __shfl_xor(a2, 16); a3 += __shfl_xor(a3, 16);
    a4 += __shfl_xor(a4, 16); a5 += __shfl_xor(a5, 16);
    a6 += __shfl_xor(a6, 16); a7 += __shfl_xor(a7, 16);
    a0 += __shfl_xor(a0, 32); a1 += __shfl_xor(a1, 32);
    a2 += __shfl_xor(a2, 32); a3 += __shfl_xor(a3, 32);
    a4 += __shfl_xor(a4, 32); a5 += __shfl_xor(a5, 32);
    a6 += __shfl_xor(a6, 32); a7 += __shfl_xor(a7, 32);
    us8 sv = *(const us8*)(Tb + (size_t)node * HID + fl * 8);
    a0 += b2f(sv[0]); a1 += b2f(sv[1]); a2 += b2f(sv[2]); a3 += b2f(sv[3]);
    a4 += b2f(sv[4]); a5 += b2f(sv[5]); a6 += b2f(sv[6]); a7 += b2f(sv[7]);
    float di = dinv[node];
    float4 b0 = *(const float4*)(bias + fl * 8);
    float4 b1v = *(const float4*)(bias + fl * 8 + 4);
    a0 = fmaxf(fmaf(di, a0, b0.x), 0.f);
    a1 = fmaxf(fmaf(di, a1, b0.y), 0.f);
    a2 = fmaxf(fmaf(di, a2, b0.z), 0.f);
    a3 = fmaxf(fmaf(di, a3, b0.w), 0.f);
    a4 = fmaxf(fmaf(di, a4, b1v.x), 0.f);
    a5 = fmaxf(fmaf(di, a5, b1v.y), 0.f);
    a6 = fmaxf(fmaf(di, a6, b1v.z), 0.f);
    a7 = fmaxf(fmaf(di, a7, b1v.w), 0.f);
    if (grp == 0) {
        us8 o;
        o[0] = f2b(a0); o[1] = f2b(a1); o[2] = f2b(a2); o[3] = f2b(a3);
        o[4] = f2b(a4); o[5] = f2b(a5); o[6] = f2b(a6); o[7] = f2b(a7);
        *(us8*)(Hb + (size_t)node * HID + fl * 8) = o;
    }
}

// ---------------- layer 3 (linear): z[i] = dinv[i] * dot(Hb[i,:], w3l) ----------------
// wave handles 8 nodes: nd=lane>>3, fl=lane&7; 1 KB coalesced loads.

__global__ __launch_bounds__(256) void k_gemv3(const unsigned short* __restrict__ Hb,
                                               const float* __restrict__ w3l,
                                               const float* __restrict__ dinv,
                                               float* __restrict__ z) {
    int t = threadIdx.x;
    int lane = t & 63, wv = t >> 6;
    int nd = lane >> 3, fl = lane & 7;
    int row = blockIdx.x * 32 + wv * 8 + nd;
    if (row >= N_NODES) return;
    us8 hv = *(const us8*)(Hb + (size_t)row * HID + fl * 8);
    float4 w0 = *(const float4*)(w3l + fl * 8);
    float4 w1 = *(const float4*)(w3l + fl * 8 + 4);
    float s = b2f(hv[0]) * w0.x + b2f(hv[1]) * w0.y + b2f(hv[2]) * w0.z +
              b2f(hv[3]) * w0.w + b2f(hv[4]) * w1.x + b2f(hv[5]) * w1.y +
              b2f(hv[6]) * w1.z + b2f(hv[7]) * w1.w;
    s += __shfl_xor(s, 1);
    s += __shfl_xor(s, 2);
    s += __shfl_xor(s, 4);
    if (fl == 0) z[row] = dinv[row] * s;
}

// scalar aggregation + pool: out[g] += b3wl + dinv[d]*(z[d] + sum z[src])
__global__ __launch_bounds__(256) void k_aggpool_s(const float* __restrict__ z,
                                                   const int* __restrict__ rowptr,
                                                   const int* __restrict__ deg,
                                                   const float* __restrict__ dinv,
                                                   const int* __restrict__ col,
                                                   const float* __restrict__ w3l,
                                                   const int* __restrict__ batch,
                                                   float* __restrict__ partial) {
    int i = blockIdx.x * 256 + threadIdx.x;
    if (i >= N_NODES) return;
    int e = rowptr[i];
    int end = e + deg[i] - 1;
    float s0 = z[i], s1 = 0.f, s2 = 0.f, s3 = 0.f;
    for (; e + 4 <= end; e += 4) {
        s0 += z[col[e]];
        s1 += z[col[e + 1]];
        s2 += z[col[e + 2]];
        s3 += z[col[e + 3]];
    }
    for (; e < end; ++e) s0 += z[col[e]];
    float s = w3l[HID] + dinv[i] * (s0 + s1 + s2 + s3);
    atomicAdd(&partial[(blockIdx.x & (NPART - 1)) * PSTRIDE + batch[i]], s);
}

__global__ void k_pool_reduce(const float* __restrict__ partial,
                              const float* __restrict__ bl,
                              float* __restrict__ out) {
    int g = threadIdx.x;
    if (g >= N_GRAPHS) return;
    float s = bl[0];
    for (int p = 0; p < NPART; ++p) s += partial[p * PSTRIDE + g];
    out[g] = s;
}

extern "C" void kernel_launch(void* const* d_in, const int* in_sizes, int n_in,
                              void* d_out, int out_size, void* d_ws, size_t ws_size,
                              hipStream_t stream) {
    const float* x     = (const float*)d_in[0];
    const int*   ei    = (const int*)d_in[1];
    const int*   batch = (const int*)d_in[2];
    const float* W1    = (const float*)d_in[3];
    const float* b1    = (const float*)d_in[4];
    const float* W2    = (const float*)d_in[5];
    const float* b2    = (const float*)d_in[6];
    const float* W3    = (const float*)d_in[7];
    const float* b3    = (const float*)d_in[8];
    const float* Wl    = (const float*)d_in[9];
    const float* bl    = (const float*)d_in[10];
    float* out = (float*)d_out;

    char* p = (char*)d_ws;
    unsigned short* tb = (unsigned short*)p; p += (size_t)N_NODES * HID * 2;  // 12.8 MB
    unsigned short* hB = (unsigned short*)p; p += (size_t)N_NODES * HID * 2;  // 12.8 MB
    int*   col     = (int*)p;   p += (size_t)(N_EDGES + 16) * 4;              // 6.4 MB
    int*   ebuck   = (int*)p;   p += (size_t)N_EDGES * 4;                     // 6.4 MB
    int*   deg     = (int*)p;   p += (size_t)N_NODES * 4;
    float* dinv    = (float*)p; p += (size_t)N_NODES * 4;
    int*   rowptr  = (int*)p;   p += (size_t)N_NODES * 4;
    float* z       = (float*)p; p += (size_t)N_NODES * 4;
    int*   bcount  = (int*)p;   p += (NBUCK + 1) * 4;
    int*   bstart  = (int*)p;   p += (NBUCK + 1) * 4;
    int*   bfill   = (int*)p;   p += (NBUCK + 1) * 4;
    int*   bsum    = (int*)p;   p += 512 * 4;
    int*   bscan   = (int*)p;   p += 512 * 4;
    float* partial = (float*)p; p += (size_t)NPART * PSTRIDE * 4;
    unsigned short* wt1 = (unsigned short*)p; p += (size_t)IN_DIM * HID * 2;
    unsigned short* wt2 = (unsigned short*)p; p += (size_t)HID * HID * 2;
    float* w3l     = (float*)p; p += 128 * 4;   // w3l[64] + b3wl at [64]

    const int* src  = ei;
    const int* dstp = ei + N_EDGES;

    const int nb = (N_NODES + 255) / 256;            // 391
    const int cb = (N_EDGES + CHUNK - 1) / CHUNK;    // 391
    const int gemm_blocks = (N_NODES + 63) / 64;     // 1563
    const int node_wave_blocks = (N_NODES + 3) / 4;  // 25000

    k_wprep<<<(IN_DIM * HID + 255) / 256, 256, 0, stream>>>(W1, W2, W3, Wl, b3,
                                                            wt1, wt2, w3l);
    k_zero_misc<<<(NPART * PSTRIDE + 255) / 256, 256, 0, stream>>>(bcount, partial);
    k_bhist<<<cb, 256, 0, stream>>>(dstp, bcount);
    k_bscan<<<1, 512, 0, stream>>>(bcount, bstart, bfill);
    k_bscatter<<<cb, 256, 0, stream>>>(src, dstp, bfill, ebuck);
    k_degscan<<<NBUCK, 256, 0, stream>>>(bstart, ebuck, deg, dinv, bsum);
    k_scan2<<<1, 512, 0, stream>>>(bsum, bscan, nb);
    k_fill2<<<NBUCK, 256, 0, stream>>>(bstart, ebuck, deg, bscan, rowptr, col);

    k_gemm1<<<gemm_blocks, 256, 0, stream>>>(x, wt1, dinv, tb);
    k_agg<<<node_wave_blocks, 256, 0, stream>>>(tb, rowptr, deg, dinv, col, b1, hB);
    k_gemm2<<<gemm_blocks, 256, 0, stream>>>(hB, wt2, dinv, tb);
    k_agg<<<node_wave_blocks, 256, 0, stream>>>(tb, rowptr, deg, dinv, col, b2, hB);

    k_gemv3<<<(N_NODES + 31) / 32, 256, 0, stream>>>(hB, w3l, dinv, z);
    k_aggpool_s<<<nb, 256, 0, stream>>>(z, rowptr, deg, dinv, col, w3l, batch, partial);

    k_pool_reduce<<<1, 128, 0, stream>>>(partial, bl, out);
}